// Round 1
// baseline (550.346 us; speedup 1.0000x reference)
//
#include <hip/hip_runtime.h>
#include <hip/hip_bf16.h>

#define NWIN 4096
#define NH 6
#define HD 32
#define NTOK 64
#define CDIM 192
#define SCALE 0.17677669529663687f

typedef __attribute__((ext_vector_type(8))) short short8;
typedef __attribute__((ext_vector_type(4))) short short4v;
typedef __attribute__((ext_vector_type(4))) float f32x4;

// LDS geometry (in shorts / bf16 elements)
#define HR 7424          // per-head region: q[64][40] | k[64][40] | vT[32][72]
#define QO 0
#define KO 2560
#define VO 5120
#define QLD 40
#define VLD 72
#define PLD 72           // P[64][72] aliases q+k (4608 <= 5120)
#define AOLD 200         // ao[64][200] bf16

__device__ __forceinline__ short bf(float x) {
  union { __hip_bfloat16 h; short s; } u;
  u.h = __float2bfloat16(x);
  return u.s;
}

__device__ __forceinline__ short8 cvt8v(f32x4 a, f32x4 b) {
  short8 r;
#pragma unroll
  for (int i = 0; i < 4; ++i) { r[i] = bf(a[i]); r[4 + i] = bf(b[i]); }
  return r;
}

__global__ __launch_bounds__(384, 2)
void swin_block_kernel(const float* __restrict__ x,
                       const float* __restrict__ qkv_w,
                       const float* __restrict__ qkv_b,
                       const float* __restrict__ proj_w,
                       const float* __restrict__ proj_b,
                       const float* __restrict__ bias_tbl,
                       float* __restrict__ out) {
  __shared__ short lds[NH * HR + NTOK * AOLD];   // 114688 bytes
  short* ao = lds + NH * HR;

  const int b = blockIdx.x;
  const int tid = threadIdx.x;
  const int w = tid >> 6;        // wave index == head index
  const int lane = tid & 63;
  const int g = lane >> 4;       // quadrant 0..3
  const int cc = lane & 15;      // 0..15

  const float* xp = x + (size_t)b * NTOK * CDIM;
  short* hreg = lds + w * HR;

  // ---------------- Stage 1: QKV projection ----------------
  f32x4 acc[3][4][2];
#pragma unroll
  for (int m = 0; m < 3; ++m)
#pragma unroll
    for (int i = 0; i < 4; ++i)
#pragma unroll
      for (int j = 0; j < 2; ++j)
        acc[m][i][j] = (f32x4){0.f, 0.f, 0.f, 0.f};

#pragma unroll
  for (int ks = 0; ks < 6; ++ks) {
    short8 afr[4];
#pragma unroll
    for (int mt = 0; mt < 4; ++mt) {
      const float* ap = xp + (mt * 16 + cc) * CDIM + ks * 32 + g * 8;
      f32x4 a0 = *(const f32x4*)ap;
      f32x4 a1 = *(const f32x4*)(ap + 4);
      afr[mt] = cvt8v(a0, a1);
    }
#pragma unroll
    for (int mat = 0; mat < 3; ++mat) {
#pragma unroll
      for (int ct = 0; ct < 2; ++ct) {
        const int o = mat * CDIM + w * 32 + ct * 16 + cc;
        const float* bp = qkv_w + o * CDIM + ks * 32 + g * 8;
        f32x4 b0 = *(const f32x4*)bp;
        f32x4 b1 = *(const f32x4*)(bp + 4);
        short8 bfr = cvt8v(b0, b1);
#pragma unroll
        for (int mt = 0; mt < 4; ++mt)
          acc[mat][mt][ct] = __builtin_amdgcn_mfma_f32_16x16x32_bf16(
              afr[mt], bfr, acc[mat][mt][ct], 0, 0, 0);
      }
    }
  }

  // add bias (+scale for q), convert to bf16, stash in LDS
#pragma unroll
  for (int mat = 0; mat < 3; ++mat) {
#pragma unroll
    for (int ct = 0; ct < 2; ++ct) {
      const int o = mat * CDIM + w * 32 + ct * 16 + cc;
      const float bv = qkv_b[o];
#pragma unroll
      for (int mt = 0; mt < 4; ++mt) {
        f32x4 v4 = acc[mat][mt][ct];
        if (mat == 2) {
          // v stored transposed: vT[d][m], 4 consecutive m -> packed 8B write
          short4v pv;
#pragma unroll
          for (int e = 0; e < 4; ++e) pv[e] = bf(v4[e] + bv);
          const int d = ct * 16 + cc;
          const int m0 = mt * 16 + g * 4;
          *(short4v*)&hreg[VO + d * VLD + m0] = pv;
        } else {
#pragma unroll
          for (int e = 0; e < 4; ++e) {
            float val = v4[e] + bv;
            if (mat == 0) val *= SCALE;
            const int r = mt * 16 + g * 4 + e;
            const int col = ct * 16 + cc;
            hreg[(mat == 0 ? QO : KO) + r * QLD + col] = bf(val);
          }
        }
      }
    }
  }

  // ---------------- Stage 2: attention (wave-private head) ----------------
  // S = (q*scale) @ k^T : 64x64, K=32 in one MFMA step
  short8 aq[4], bk[4];
#pragma unroll
  for (int t = 0; t < 4; ++t) {
    aq[t] = *(const short8*)&hreg[QO + (t * 16 + cc) * QLD + g * 8];
    bk[t] = *(const short8*)&hreg[KO + (t * 16 + cc) * QLD + g * 8];
  }
  f32x4 sacc[4][4];
#pragma unroll
  for (int nt = 0; nt < 4; ++nt)
#pragma unroll
    for (int mt = 0; mt < 4; ++mt)
      sacc[nt][mt] = (f32x4){0.f, 0.f, 0.f, 0.f};
#pragma unroll
  for (int nt = 0; nt < 4; ++nt)
#pragma unroll
    for (int mt = 0; mt < 4; ++mt)
      sacc[nt][mt] = __builtin_amdgcn_mfma_f32_16x16x32_bf16(
          aq[nt], bk[mt], sacc[nt][mt], 0, 0, 0);

  // relative-position bias + row softmax (row spread over 16 lanes, 4 m-tiles)
#pragma unroll
  for (int nt = 0; nt < 4; ++nt) {
#pragma unroll
    for (int e = 0; e < 4; ++e) {
      const int n = nt * 16 + g * 4 + e;
      const int y1 = n >> 3, x1 = n & 7;
      float sv[4];
      float mx = -1e30f;
#pragma unroll
      for (int mt = 0; mt < 4; ++mt) {
        const int m = mt * 16 + cc;
        const int y2 = m >> 3, x2 = m & 7;
        const int idx = (y1 - y2 + 7) * 15 + (x1 - x2 + 7);
        float s = sacc[nt][mt][e] + bias_tbl[idx * NH + w];
        sv[mt] = s;
        mx = fmaxf(mx, s);
      }
#pragma unroll
      for (int off = 8; off >= 1; off >>= 1)
        mx = fmaxf(mx, __shfl_xor(mx, off, 16));
      float sum = 0.f;
#pragma unroll
      for (int mt = 0; mt < 4; ++mt) {
        sv[mt] = __expf(sv[mt] - mx);
        sum += sv[mt];
      }
#pragma unroll
      for (int off = 8; off >= 1; off >>= 1)
        sum += __shfl_xor(sum, off, 16);
      const float rinv = 1.0f / sum;
#pragma unroll
      for (int mt = 0; mt < 4; ++mt)
        hreg[n * PLD + mt * 16 + cc] = bf(sv[mt] * rinv);  // P aliases q/k (dead)
    }
  }

  // out_h = P @ v : 64x32, K=64 in two steps; v read from vT rows (contiguous)
  f32x4 oacc[4][2];
#pragma unroll
  for (int nt = 0; nt < 4; ++nt)
#pragma unroll
    for (int dt = 0; dt < 2; ++dt)
      oacc[nt][dt] = (f32x4){0.f, 0.f, 0.f, 0.f};
#pragma unroll
  for (int ks = 0; ks < 2; ++ks) {
    short8 apf[4];
#pragma unroll
    for (int nt = 0; nt < 4; ++nt)
      apf[nt] = *(const short8*)&hreg[(nt * 16 + cc) * PLD + ks * 32 + g * 8];
#pragma unroll
    for (int dt = 0; dt < 2; ++dt) {
      short8 bv = *(const short8*)&hreg[VO + (dt * 16 + cc) * VLD + ks * 32 + g * 8];
#pragma unroll
      for (int nt = 0; nt < 4; ++nt)
        oacc[nt][dt] = __builtin_amdgcn_mfma_f32_16x16x32_bf16(
            apf[nt], bv, oacc[nt][dt], 0, 0, 0);
    }
  }

  // deposit this head's output slice into the shared ao tile (bf16)
#pragma unroll
  for (int nt = 0; nt < 4; ++nt)
#pragma unroll
    for (int dt = 0; dt < 2; ++dt)
#pragma unroll
      for (int e = 0; e < 4; ++e)
        ao[(nt * 16 + g * 4 + e) * AOLD + w * 32 + dt * 16 + cc] =
            bf(oacc[nt][dt][e]);

  __syncthreads();

  // ---------------- Stage 3: output projection ----------------
  f32x4 pacc[4][2];
#pragma unroll
  for (int mt = 0; mt < 4; ++mt)
#pragma unroll
    for (int jt = 0; jt < 2; ++jt)
      pacc[mt][jt] = (f32x4){0.f, 0.f, 0.f, 0.f};

#pragma unroll
  for (int ks = 0; ks < 6; ++ks) {
    short8 afr[4];
#pragma unroll
    for (int mt = 0; mt < 4; ++mt)
      afr[mt] = *(const short8*)&ao[(mt * 16 + cc) * AOLD + ks * 32 + g * 8];
#pragma unroll
    for (int jt = 0; jt < 2; ++jt) {
      const int j = w * 32 + jt * 16 + cc;
      const float* bp = proj_w + j * CDIM + ks * 32 + g * 8;
      f32x4 b0 = *(const f32x4*)bp;
      f32x4 b1 = *(const f32x4*)(bp + 4);
      short8 bfr = cvt8v(b0, b1);
#pragma unroll
      for (int mt = 0; mt < 4; ++mt)
        pacc[mt][jt] = __builtin_amdgcn_mfma_f32_16x16x32_bf16(
            afr[mt], bfr, pacc[mt][jt], 0, 0, 0);
    }
  }

  float* op = out + (size_t)b * NTOK * CDIM;
#pragma unroll
  for (int jt = 0; jt < 2; ++jt) {
    const int j = w * 32 + jt * 16 + cc;
    const float pb = proj_b[j];
#pragma unroll
    for (int mt = 0; mt < 4; ++mt)
#pragma unroll
      for (int e = 0; e < 4; ++e)
        op[(mt * 16 + g * 4 + e) * CDIM + j] = pacc[mt][jt][e] + pb;
  }
}

extern "C" void kernel_launch(void* const* d_in, const int* in_sizes, int n_in,
                              void* d_out, int out_size, void* d_ws, size_t ws_size,
                              hipStream_t stream) {
  const float* x       = (const float*)d_in[0];
  const float* qkv_w   = (const float*)d_in[1];
  const float* qkv_b   = (const float*)d_in[2];
  const float* proj_w  = (const float*)d_in[3];
  const float* proj_b  = (const float*)d_in[4];
  const float* rel_tbl = (const float*)d_in[5];
  float* out = (float*)d_out;

  swin_block_kernel<<<NWIN, 384, 0, stream>>>(x, qkv_w, qkv_b, proj_w, proj_b,
                                              rel_tbl, out);
}

// Round 2
// 407.870 us; speedup vs baseline: 1.3493x; 1.3493x over previous
//
#include <hip/hip_runtime.h>
#include <hip/hip_bf16.h>

#define NWIN 4096
#define NH 6
#define NTOK 64
#define CDIM 192
#define SCALE 0.17677669529663687f

typedef __attribute__((ext_vector_type(8))) short short8;
typedef __attribute__((ext_vector_type(4))) short short4v;
typedef __attribute__((ext_vector_type(4))) float f32x4;

__device__ __forceinline__ short bf(float x) {
  union { __hip_bfloat16 h; short s; } u;
  u.h = __float2bfloat16(x);
  return u.s;
}

__device__ __forceinline__ short8 cvt8v(f32x4 a, f32x4 b) {
  short8 r;
#pragma unroll
  for (int i = 0; i < 4; ++i) { r[i] = bf(a[i]); r[4 + i] = bf(b[i]); }
  return r;
}

// ---------- prep: fp32 weights -> bf16 in d_ws; SCALE folded into Wq ----------
__global__ void prep_weights(const float* __restrict__ qkv_w,
                             const float* __restrict__ proj_w,
                             short* __restrict__ wbuf) {
  const int i = blockIdx.x * 256 + threadIdx.x;   // 576*256 = 147456 exactly
  if (i < 110592) {
    float v = qkv_w[i];
    if (i < 36864) v *= SCALE;                    // q rows (first 192 rows of 576)
    wbuf[i] = bf(v);
  } else {
    wbuf[i] = bf(proj_w[i - 110592]);
  }
}

// LDS plan (shorts):
//   regA = lds[0 .. 12287]   : 24576 B, three lives separated by barriers:
//          (1) x bf16 [64][192] swizzled  (2) vT per head [32][64] (w*2048)
//          (3) ao [64][192] swizzled
//   regB = lds[12288 ..]     : per-head [64][64] q(cols 0-31)|k(cols 32-63);
//          P [64][64] aliases it after q/k frags are in registers.
// All tiles XOR-swizzled: short index = r*S + (c ^ ((r&7)<<3)).

__global__ __launch_bounds__(384, 3)
void swin_block_kernel(const float* __restrict__ x,
                       const short* __restrict__ wq,    // [576][192] bf16, q pre-scaled
                       const float* __restrict__ qkv_b,
                       const short* __restrict__ wp,    // [192][192] bf16
                       const float* __restrict__ proj_b,
                       const float* __restrict__ bias_tbl,
                       float* __restrict__ out) {
  __shared__ short lds[36864];                    // 73728 B -> 2 blocks/CU
  short* const regA = lds;
  short* const regB = lds + 12288;

  const int b = blockIdx.x;
  const int tid = threadIdx.x;
  const int w = tid >> 6;         // wave == head
  const int lane = tid & 63;
  const int g = lane >> 4;
  const int cc = lane & 15;

  const float* xp = x + (size_t)b * (NTOK * CDIM);

  // ---------------- stage 0: cooperative x -> bf16 LDS ----------------
#pragma unroll
  for (int it = 0; it < 2; ++it) {
    const int flat = (tid + it * 384) * 16;       // 16 floats per thread-iter
    const int r = flat / CDIM;
    const int c = flat % CDIM;                    // multiple of 16
    const int X = (r & 7) << 3;
    f32x4 a0 = *(const f32x4*)(xp + flat);
    f32x4 a1 = *(const f32x4*)(xp + flat + 4);
    f32x4 a2 = *(const f32x4*)(xp + flat + 8);
    f32x4 a3 = *(const f32x4*)(xp + flat + 12);
    *(short8*)&regA[r * CDIM + (c ^ X)] = cvt8v(a0, a1);
    *(short8*)&regA[r * CDIM + ((c + 8) ^ X)] = cvt8v(a2, a3);
  }
  __syncthreads();

  // ---------------- stage 1: QKV projection ----------------
  f32x4 acc[3][4][2];
#pragma unroll
  for (int m = 0; m < 3; ++m)
#pragma unroll
    for (int i = 0; i < 4; ++i)
#pragma unroll
      for (int j = 0; j < 2; ++j)
        acc[m][i][j] = (f32x4){0.f, 0.f, 0.f, 0.f};

#pragma unroll
  for (int ks = 0; ks < 6; ++ks) {
    short8 afr[4];
#pragma unroll
    for (int mt = 0; mt < 4; ++mt) {
      const int r = mt * 16 + cc;
      afr[mt] = *(const short8*)&regA[r * CDIM + ((ks * 32 + g * 8) ^ ((r & 7) << 3))];
    }
#pragma unroll
    for (int mat = 0; mat < 3; ++mat) {
#pragma unroll
      for (int ct = 0; ct < 2; ++ct) {
        const int o = mat * CDIM + w * 32 + ct * 16 + cc;
        short8 bfr = *(const short8*)&wq[o * CDIM + ks * 32 + g * 8];
#pragma unroll
        for (int mt = 0; mt < 4; ++mt)
          acc[mat][mt][ct] = __builtin_amdgcn_mfma_f32_16x16x32_bf16(
              afr[mt], bfr, acc[mat][mt][ct], 0, 0, 0);
      }
    }
  }
  __syncthreads();   // x dead -> regA becomes vT

  short* const qk = regB + w * 4096;   // [64][64] q|k, later P
  short* const vt = regA + w * 2048;   // [32][64] vT

#pragma unroll
  for (int mat = 0; mat < 3; ++mat) {
#pragma unroll
    for (int ct = 0; ct < 2; ++ct) {
      const int o = mat * CDIM + w * 32 + ct * 16 + cc;
      float bv = qkv_b[o];
      if (mat == 0) bv *= SCALE;       // weights pre-scaled; scale bias to match
#pragma unroll
      for (int mt = 0; mt < 4; ++mt) {
        f32x4 v4 = acc[mat][mt][ct];
        if (mat == 2) {
          short4v pv;
#pragma unroll
          for (int e = 0; e < 4; ++e) pv[e] = bf(v4[e] + bv);
          const int d = ct * 16 + cc;        // vT row (head dim)
          const int m0 = mt * 16 + g * 4;    // vT col (token)
          *(short4v*)&vt[d * 64 + (m0 ^ ((d & 7) << 3))] = pv;
        } else {
          const int cbase = (mat == 1 ? 32 : 0) + ct * 16 + cc;
#pragma unroll
          for (int e = 0; e < 4; ++e) {
            const int r = mt * 16 + g * 4 + e;
            qk[r * 64 + (cbase ^ ((r & 7) << 3))] = bf(v4[e] + bv);
          }
        }
      }
    }
  }

  // ---------------- stage 2: attention (wave-private head) ----------------
  short8 aq[4], bk[4];
#pragma unroll
  for (int t = 0; t < 4; ++t) {
    const int r = t * 16 + cc;
    const int X = (r & 7) << 3;
    aq[t] = *(const short8*)&qk[r * 64 + ((g * 8) ^ X)];
    bk[t] = *(const short8*)&qk[r * 64 + ((32 + g * 8) ^ X)];
  }
  f32x4 sacc[4][4];
#pragma unroll
  for (int nt = 0; nt < 4; ++nt)
#pragma unroll
    for (int mt = 0; mt < 4; ++mt)
      sacc[nt][mt] = (f32x4){0.f, 0.f, 0.f, 0.f};
#pragma unroll
  for (int nt = 0; nt < 4; ++nt)
#pragma unroll
    for (int mt = 0; mt < 4; ++mt)
      sacc[nt][mt] = __builtin_amdgcn_mfma_f32_16x16x32_bf16(
          aq[nt], bk[mt], sacc[nt][mt], 0, 0, 0);

  // bias + softmax; P written into qk (q/k dead)
#pragma unroll
  for (int nt = 0; nt < 4; ++nt) {
#pragma unroll
    for (int e = 0; e < 4; ++e) {
      const int n = nt * 16 + g * 4 + e;
      const int y1 = n >> 3, x1 = n & 7;
      float sv[4];
      float mx = -1e30f;
#pragma unroll
      for (int mt = 0; mt < 4; ++mt) {
        const int m = mt * 16 + cc;
        const int idx = (y1 - (m >> 3) + 7) * 15 + (x1 - (m & 7) + 7);
        float s = sacc[nt][mt][e] + bias_tbl[idx * NH + w];
        sv[mt] = s;
        mx = fmaxf(mx, s);
      }
#pragma unroll
      for (int off = 8; off >= 1; off >>= 1)
        mx = fmaxf(mx, __shfl_xor(mx, off, 16));
      float sum = 0.f;
#pragma unroll
      for (int mt = 0; mt < 4; ++mt) {
        sv[mt] = __expf(sv[mt] - mx);
        sum += sv[mt];
      }
#pragma unroll
      for (int off = 8; off >= 1; off >>= 1)
        sum += __shfl_xor(sum, off, 16);
      const float rinv = 1.0f / sum;
      const int Xn = (n & 7) << 3;
#pragma unroll
      for (int mt = 0; mt < 4; ++mt)
        qk[n * 64 + ((mt * 16 + cc) ^ Xn)] = bf(sv[mt] * rinv);
    }
  }

  // PV: out_h = P @ v, K = 64 in two steps; v from vT rows
  f32x4 oacc[4][2];
#pragma unroll
  for (int nt = 0; nt < 4; ++nt)
#pragma unroll
    for (int dt = 0; dt < 2; ++dt)
      oacc[nt][dt] = (f32x4){0.f, 0.f, 0.f, 0.f};
#pragma unroll
  for (int ks = 0; ks < 2; ++ks) {
    short8 apf[4];
#pragma unroll
    for (int nt = 0; nt < 4; ++nt) {
      const int r = nt * 16 + cc;
      apf[nt] = *(const short8*)&qk[r * 64 + ((ks * 32 + g * 8) ^ ((r & 7) << 3))];
    }
#pragma unroll
    for (int dt = 0; dt < 2; ++dt) {
      const int d = dt * 16 + cc;
      short8 bv8 = *(const short8*)&vt[d * 64 + ((ks * 32 + g * 8) ^ ((d & 7) << 3))];
#pragma unroll
      for (int nt = 0; nt < 4; ++nt)
        oacc[nt][dt] = __builtin_amdgcn_mfma_f32_16x16x32_bf16(
            apf[nt], bv8, oacc[nt][dt], 0, 0, 0);
    }
  }

  __syncthreads();   // all P/vT reads done -> regA becomes ao

#pragma unroll
  for (int nt = 0; nt < 4; ++nt)
#pragma unroll
    for (int dt = 0; dt < 2; ++dt)
#pragma unroll
      for (int e = 0; e < 4; ++e) {
        const int r = nt * 16 + g * 4 + e;
        const int c = w * 32 + dt * 16 + cc;
        regA[r * CDIM + (c ^ ((r & 7) << 3))] = bf(oacc[nt][dt][e]);
      }
  __syncthreads();

  // ---------------- stage 3: output projection ----------------
  f32x4 pacc[4][2];
#pragma unroll
  for (int mt = 0; mt < 4; ++mt)
#pragma unroll
    for (int jt = 0; jt < 2; ++jt)
      pacc[mt][jt] = (f32x4){0.f, 0.f, 0.f, 0.f};

#pragma unroll
  for (int ks = 0; ks < 6; ++ks) {
    short8 afr[4];
#pragma unroll
    for (int mt = 0; mt < 4; ++mt) {
      const int r = mt * 16 + cc;
      afr[mt] = *(const short8*)&regA[r * CDIM + ((ks * 32 + g * 8) ^ ((r & 7) << 3))];
    }
#pragma unroll
    for (int jt = 0; jt < 2; ++jt) {
      const int j = w * 32 + jt * 16 + cc;
      short8 bfr = *(const short8*)&wp[j * CDIM + ks * 32 + g * 8];
#pragma unroll
      for (int mt = 0; mt < 4; ++mt)
        pacc[mt][jt] = __builtin_amdgcn_mfma_f32_16x16x32_bf16(
            afr[mt], bfr, pacc[mt][jt], 0, 0, 0);
    }
  }

  float* op = out + (size_t)b * (NTOK * CDIM);
#pragma unroll
  for (int jt = 0; jt < 2; ++jt) {
    const int j = w * 32 + jt * 16 + cc;
    const float pb = proj_b[j];
#pragma unroll
    for (int mt = 0; mt < 4; ++mt)
#pragma unroll
      for (int e = 0; e < 4; ++e)
        op[(mt * 16 + g * 4 + e) * CDIM + j] = pacc[mt][jt][e] + pb;
  }
}

extern "C" void kernel_launch(void* const* d_in, const int* in_sizes, int n_in,
                              void* d_out, int out_size, void* d_ws, size_t ws_size,
                              hipStream_t stream) {
  const float* x       = (const float*)d_in[0];
  const float* qkv_w   = (const float*)d_in[1];
  const float* qkv_b   = (const float*)d_in[2];
  const float* proj_w  = (const float*)d_in[3];
  const float* proj_b  = (const float*)d_in[4];
  const float* rel_tbl = (const float*)d_in[5];
  float* out = (float*)d_out;
  short* wbuf = (short*)d_ws;                   // 147456 shorts = 294912 B

  prep_weights<<<576, 256, 0, stream>>>(qkv_w, proj_w, wbuf);
  swin_block_kernel<<<NWIN, 384, 0, stream>>>(x, wbuf, qkv_b, wbuf + 110592,
                                              proj_b, rel_tbl, out);
}